// Round 2
// baseline (6929.462 us; speedup 1.0000x reference)
//
#include <hip/hip_runtime.h>
#include <stdint.h>

#define Kn 64
#define En 256
#define Bn 512
#define Hn 512
#define Dn 128
#define NB 256       // blocks (2 samples each)
#define NT 1024      // 16 waves
#define DT_C 0.05f

// ws layout (bytes):
//   [0, 131072)        pos  (int, Kn*Bn)  : pos[k*Bn+b] = e or -1
//   [131072, 131080)   acc  (float x2)    : loss, tot_m
//   [131584, ...)      packed bf16 weights (uint16), read as uint4 (8 bf16)
// uint32-pair offsets: W1 0, W2 131072, Wp1 262144, Wp2 393216,
//                      Wi 425984, Wf 589824, Wo 753664, Wc 917504

__device__ __forceinline__ float bflo(uint32_t w){ return __uint_as_float(w << 16); }
__device__ __forceinline__ float bfhi(uint32_t w){ return __uint_as_float(w & 0xffff0000u); }
__device__ __forceinline__ float sigm(float x){ return 1.0f/(1.0f + __expf(-x)); }

__global__ void k_init(int* __restrict__ pos, float* __restrict__ acc){
  int i = blockIdx.x*blockDim.x + threadIdx.x;
  if (i < Kn*Bn) pos[i] = -1;
  if (i < 2) acc[i] = 0.0f;
}

__global__ void k_scatter(const int* __restrict__ bidx, int* __restrict__ pos){
  int i = blockIdx.x*blockDim.x + threadIdx.x;
  if (i < Kn*En){
    int k = i >> 8;           // En = 256
    int e = i & (En-1);
    pos[(k << 9) | bidx[i]] = e;   // Bn = 512
  }
}

__global__ void k_cvt(const float* __restrict__ src, uint16_t* __restrict__ dst, int n){
  int i = blockIdx.x*blockDim.x + threadIdx.x;
  if (i < n){
    uint32_t u = __float_as_uint(src[i]);
    uint32_t r = (u + 0x7fffu + ((u >> 16) & 1u)) >> 16;  // RNE
    dst[i] = (uint16_t)r;
  }
}

// 16 FMAs (8 cols x 2 samples) from one uint4 (8 bf16 weights)
#define UNPACK_FMA16(HX, HY, W) do{                                   \
  float _q0=bflo((W).x), _q1=bfhi((W).x), _q2=bflo((W).y), _q3=bfhi((W).y); \
  float _q4=bflo((W).z), _q5=bfhi((W).z), _q6=bflo((W).w), _q7=bfhi((W).w); \
  a0[0]=fmaf((HX),_q0,a0[0]); a1[0]=fmaf((HY),_q0,a1[0]);             \
  a0[1]=fmaf((HX),_q1,a0[1]); a1[1]=fmaf((HY),_q1,a1[1]);             \
  a0[2]=fmaf((HX),_q2,a0[2]); a1[2]=fmaf((HY),_q2,a1[2]);             \
  a0[3]=fmaf((HX),_q3,a0[3]); a1[3]=fmaf((HY),_q3,a1[3]);             \
  a0[4]=fmaf((HX),_q4,a0[4]); a1[4]=fmaf((HY),_q4,a1[4]);             \
  a0[5]=fmaf((HX),_q5,a0[5]); a1[5]=fmaf((HY),_q5,a1[5]);             \
  a0[6]=fmaf((HX),_q6,a0[6]); a1[6]=fmaf((HY),_q6,a1[6]);             \
  a0[7]=fmaf((HX),_q7,a0[7]); a1[7]=fmaf((HY),_q7,a1[7]);             \
}while(0)

// dot over 512-row matrix (64 uint4/row); thread (cg,kc): cols cg*8..+8, rows kc*32..+32
__device__ __forceinline__ void dot512(const float2* __restrict__ Hb,
                                       const uint4* __restrict__ Wq,
                                       float* __restrict__ part, int cg, int kc)
{
  float a0[8], a1[8];
  #pragma unroll
  for (int i=0;i<8;i++){ a0[i]=0.f; a1[i]=0.f; }
  const int r0 = kc*32;
  #pragma unroll 8
  for (int i=0;i<32;i++){
    float2 h = Hb[r0+i];
    uint4  w = Wq[(size_t)(r0+i)*64 + cg];
    UNPACK_FMA16(h.x, h.y, w);
  }
  float* pb = part + kc*1024 + cg*8;
  *(float4*)(pb)       = make_float4(a0[0],a0[1],a0[2],a0[3]);
  *(float4*)(pb+4)     = make_float4(a0[4],a0[5],a0[6],a0[7]);
  *(float4*)(pb+512)   = make_float4(a1[0],a1[1],a1[2],a1[3]);
  *(float4*)(pb+516)   = make_float4(a1[4],a1[5],a1[6],a1[7]);
}

// gate dot over [X(128) ; H(512)] rows (64 uint4/row)
__device__ __forceinline__ void dot640(const float2* __restrict__ Xb,
                                       const float2* __restrict__ Hb,
                                       const uint4* __restrict__ Wq,
                                       float* __restrict__ part, int cg, int kc)
{
  float a0[8], a1[8];
  #pragma unroll
  for (int i=0;i<8;i++){ a0[i]=0.f; a1[i]=0.f; }
  const int rx = kc*8;
  #pragma unroll
  for (int i=0;i<8;i++){
    float2 h = Xb[rx+i];
    uint4  w = Wq[(size_t)(rx+i)*64 + cg];
    UNPACK_FMA16(h.x, h.y, w);
  }
  const int rh = kc*32;
  #pragma unroll 8
  for (int i=0;i<32;i++){
    float2 h = Hb[rh+i];
    uint4  w = Wq[(size_t)(Dn + rh + i)*64 + cg];
    UNPACK_FMA16(h.x, h.y, w);
  }
  float* pb = part + kc*1024 + cg*8;
  *(float4*)(pb)       = make_float4(a0[0],a0[1],a0[2],a0[3]);
  *(float4*)(pb+4)     = make_float4(a0[4],a0[5],a0[6],a0[7]);
  *(float4*)(pb+512)   = make_float4(a1[0],a1[1],a1[2],a1[3]);
  *(float4*)(pb+516)   = make_float4(a1[4],a1[5],a1[6],a1[7]);
}

// Wp2: 512 rows x 128 cols (16 uint4/row); thread (cg4,kc2): cols cg4*8, rows kc2*8..+8
__device__ __forceinline__ void dot_p2(const float2* __restrict__ Tb,
                                       const uint4* __restrict__ Wq,
                                       float* __restrict__ part, int cg4, int kc2)
{
  float a0[8], a1[8];
  #pragma unroll
  for (int i=0;i<8;i++){ a0[i]=0.f; a1[i]=0.f; }
  const int r0 = kc2*8;
  #pragma unroll
  for (int i=0;i<8;i++){
    float2 h = Tb[r0+i];
    uint4  w = Wq[(size_t)(r0+i)*16 + cg4];
    UNPACK_FMA16(h.x, h.y, w);
  }
  float* pb = part + kc2*256 + cg4*8;
  *(float4*)(pb)       = make_float4(a0[0],a0[1],a0[2],a0[3]);
  *(float4*)(pb+4)     = make_float4(a0[4],a0[5],a0[6],a0[7]);
  *(float4*)(pb+128)   = make_float4(a1[0],a1[1],a1[2],a1[3]);
  *(float4*)(pb+132)   = make_float4(a1[4],a1[5],a1[6],a1[7]);
}

__device__ __forceinline__ float reduce16(const float* __restrict__ part, int s, int j){
  float sum = 0.f;
  #pragma unroll
  for (int q=0;q<16;q++) sum += part[q*1024 + s*512 + j];
  return sum;
}

__global__ __launch_bounds__(NT) void k_main(
  const float* __restrict__ X, const float* __restrict__ Mm,
  const int* __restrict__ pos, const uint32_t* __restrict__ Wb,
  const float* __restrict__ bi_, const float* __restrict__ bf_,
  const float* __restrict__ bo_, const float* __restrict__ bc_,
  const float* __restrict__ b1_, const float* __restrict__ b2_,
  const float* __restrict__ bp1_, const float* __restrict__ bp2_,
  float* __restrict__ acc)
{
  const uint4* Wq   = (const uint4*)Wb;
  const uint4* W1q  = Wq;
  const uint4* W2q  = Wq + 32768;
  const uint4* Wp1q = Wq + 65536;
  const uint4* Wp2q = Wq + 98304;
  const uint4* Wgq[4] = { Wq+106496, Wq+147456, Wq+188416, Wq+229376 };

  const int t  = threadIdx.x;
  const int b  = blockIdx.x;
  const int j  = t & 511;
  const int s  = t >> 9;
  const int cg = t & 63;
  const int kc = t >> 6;     // 0..15
  const int cg4 = t & 15;
  const int kc2 = t >> 4;    // 0..63

  __shared__ float2 sh_h[Hn];
  __shared__ float2 sh_t[Hn];
  __shared__ float  sh_c[2*Hn];
  __shared__ float2 sh_x[Dn];
  __shared__ float  part[16*1024];
  __shared__ float  red[32];

  ((float*)sh_h)[t] = 0.f;
  sh_c[t] = 0.f;

  const float vb1 = b1_[j], vb2 = b2_[j], vbp1 = bp1_[j];
  const float vgb0 = bi_[j], vgb1 = bf_[j], vgb2 = bo_[j], vgb3 = bc_[j];
  float vbp2 = 0.f;
  if (t < 2*Dn) vbp2 = bp2_[t & (Dn-1)];

  float loss_loc = 0.f, m_loc = 0.f;

  for (int k=0;k<Kn;k++){
    const int e0 = pos[(k<<9) + 2*b];
    const int e1 = pos[(k<<9) + 2*b + 1];
    const bool obs = (e0 >= 0) || (e1 >= 0);
    if (k == Kn-1 && !obs) break;    // block-uniform

    // ---- 2 Euler steps (both samples) ----
    for (int st=0; st<2; st++){
      __syncthreads();                          // h stable, part free
      dot512(sh_h, W1q, part, cg, kc);
      __syncthreads();
      { float v = tanhf(reduce16(part, s, j) + vb1);
        __syncthreads();                        // part reads done before reuse marker
        ((float*)sh_t)[2*j+s] = v; }
      __syncthreads();                          // t ready
      dot512(sh_t, W2q, part, cg, kc);
      __syncthreads();
      ((float*)sh_h)[2*j+s] += DT_C * (reduce16(part, s, j) + vb2);
    }
    __syncthreads();                            // h updated, part reads done

    if (!obs) continue;

    // stage X rows (zeros for unobserved sample)
    if (t < 2*Dn){
      int s2 = t >> 7, d = t & (Dn-1);
      int es = s2 ? e1 : e0;
      float v = 0.f;
      if (es >= 0) v = X[((size_t)(k*En+es))*Dn + d];
      ((float*)sh_x)[2*d + s2] = v;
    }
    // p_model layer 1
    dot512(sh_h, Wp1q, part, cg, kc);
    __syncthreads();                            // also covers sh_x
    { float v = fmaxf(reduce16(part, s, j) + vbp1, 0.f);
      __syncthreads();
      ((float*)sh_t)[2*j+s] = v; }
    __syncthreads();
    // p_model layer 2 + loss
    dot_p2(sh_t, Wp2q, part, cg4, kc2);
    __syncthreads();
    if (t < 2*Dn){
      int s2 = t >> 7, d = t & (Dn-1);
      int es = s2 ? e1 : e0;
      if (es >= 0){
        float p = vbp2;
        #pragma unroll
        for (int q=0;q<64;q++) p += part[q*256 + s2*128 + d];
        float m  = Mm[((size_t)(k*En+es))*Dn + d];
        float xo = ((float*)sh_x)[2*d + s2];
        loss_loc += fabsf(xo - p) * m;
        m_loc    += m;
      }
    }
    __syncthreads();                            // part free for gates

    // LSTM gates (dead at last event)
    if (k < Kn-1){
      float gpre[4];
      #pragma unroll
      for (int g=0; g<4; g++){
        dot640(sh_x, sh_h, Wgq[g], part, cg, kc);
        __syncthreads();
        gpre[g] = reduce16(part, s, j);
        __syncthreads();
      }
      const int es = s ? e1 : e0;
      if (es >= 0){
        float ig = sigm(gpre[0] + vgb0), fg = sigm(gpre[1] + vgb1);
        float og = sigm(gpre[2] + vgb2), ct = tanhf(gpre[3] + vgb3);
        float cold = sh_c[2*j+s];
        float cn = fg*cold + ig*ct;
        sh_c[2*j+s] = cn;
        ((float*)sh_h)[2*j+s] = og * tanhf(cn);
      }
    }
  }

  // block reduction -> global atomics
  #pragma unroll
  for (int off=32; off>0; off>>=1){
    loss_loc += __shfl_down(loss_loc, off);
    m_loc    += __shfl_down(m_loc, off);
  }
  const int wid = t >> 6, lane = t & 63;
  if (lane == 0){ red[wid] = loss_loc; red[16+wid] = m_loc; }
  __syncthreads();
  if (t == 0){
    float L = 0.f, Mt = 0.f;
    #pragma unroll
    for (int w2=0; w2<16; w2++){ L += red[w2]; Mt += red[16+w2]; }
    atomicAdd(acc+0, L);
    atomicAdd(acc+1, Mt);
  }
}

__global__ void k_fin(const float* __restrict__ acc, float* __restrict__ out){
  if (threadIdx.x == 0){
    out[0] = acc[0];
    out[1] = acc[0]/acc[1];
  }
}

extern "C" void kernel_launch(void* const* d_in, const int* in_sizes, int n_in,
                              void* d_out, int out_size, void* d_ws, size_t ws_size,
                              hipStream_t stream)
{
  const float* X   = (const float*)d_in[0];
  const float* Mm  = (const float*)d_in[1];
  const int*  bidx = (const int*)d_in[2];
  // d_in[3] = sample_idx (unused, arange)
  const float* Wi  = (const float*)d_in[4];
  const float* bi  = (const float*)d_in[5];
  const float* Wf  = (const float*)d_in[6];
  const float* bff = (const float*)d_in[7];
  const float* Wo  = (const float*)d_in[8];
  const float* bo  = (const float*)d_in[9];
  const float* Wc  = (const float*)d_in[10];
  const float* bc  = (const float*)d_in[11];
  const float* W1  = (const float*)d_in[12];
  const float* b1  = (const float*)d_in[13];
  const float* W2  = (const float*)d_in[14];
  const float* b2  = (const float*)d_in[15];
  const float* Wp1 = (const float*)d_in[16];
  const float* bp1 = (const float*)d_in[17];
  const float* Wp2 = (const float*)d_in[18];
  const float* bp2 = (const float*)d_in[19];

  char* ws = (char*)d_ws;
  int*      pos  = (int*)ws;
  float*    acc  = (float*)(ws + 131072);
  uint16_t* wb16 = (uint16_t*)(ws + 131584);
  uint32_t* wb32 = (uint32_t*)(ws + 131584);

  k_init   <<<(Kn*Bn + 255)/256, 256, 0, stream>>>(pos, acc);
  k_scatter<<<(Kn*En + 255)/256, 256, 0, stream>>>(bidx, pos);

  struct { const float* s; size_t off; int n; } cv[8] = {
    { W1,       0, Hn*Hn },
    { W2,  131072, Hn*Hn },
    { Wp1, 262144, Hn*Hn },
    { Wp2, 393216, Hn*Dn },
    { Wi,  425984, (Dn+Hn)*Hn },
    { Wf,  589824, (Dn+Hn)*Hn },
    { Wo,  753664, (Dn+Hn)*Hn },
    { Wc,  917504, (Dn+Hn)*Hn },
  };
  for (int i=0;i<8;i++)
    k_cvt<<<(cv[i].n + 255)/256, 256, 0, stream>>>(cv[i].s, wb16 + cv[i].off*2, cv[i].n);

  k_main<<<NB, NT, 0, stream>>>(X, Mm, pos, wb32,
                                bi, bff, bo, bc, b1, b2, bp1, bp2, acc);
  k_fin<<<1, 64, 0, stream>>>(acc, (float*)d_out);
}